// Round 2
// baseline (1405.238 us; speedup 1.0000x reference)
//
#include <hip/hip_runtime.h>
#include <float.h>

// Problem constants
constexpr int D      = 256;     // code dim
constexpr int K      = 8192;    // n codes
constexpr int NROWS  = 16384;   // 16 * 32 * 32
constexpr int BHW    = 1024;    // 32*32 spatial per batch

// GEMM tiling
constexpr int TM    = 128;            // rows per block
constexpr int TK    = 128;            // codes per k-chunk
constexpr int DC    = 32;             // d per LDS stage
constexpr int KPART = 4;              // k splits (grid.y)
constexpr int KSLICE = K / KPART;     // 2048
constexpr int LSTR  = 132;            // padded LDS row stride (floats)

// ---- contraction-proof f32 ops (must round exactly like numpy's elementwise)
__device__ __forceinline__ float mul_rn(float a, float b) {
#pragma clang fp contract(off)
    return a * b;
}
__device__ __forceinline__ float add_rn(float a, float b) {
#pragma clang fp contract(off)
    return a + b;
}
__device__ __forceinline__ float sub_rn(float a, float b) {
#pragma clang fp contract(off)
    return a - b;
}

// numpy pairwise_sum replica for 256 contiguous f32 squares:
// total = B(a[0:128]) + B(a[128:256]);  B = 8 chains stride 8, tree combine.
// LOAD(d) must return element d of the row.
template <typename LOAD>
__device__ __forceinline__ float np_sumsq_256(LOAD ld) {
    float blk[2];
    #pragma unroll
    for (int h = 0; h < 2; ++h) {
        const int base = h * 128;
        float r[8];
        #pragma unroll
        for (int j = 0; j < 8; ++j) {
            float v = ld(base + j);
            r[j] = mul_rn(v, v);
        }
        for (int i = 8; i < 128; i += 8) {
            #pragma unroll
            for (int j = 0; j < 8; ++j) {
                float v = ld(base + i + j);
                r[j] = add_rn(r[j], mul_rn(v, v));
            }
        }
        blk[h] = add_rn(add_rn(add_rn(r[0], r[1]), add_rn(r[2], r[3])),
                        add_rn(add_rn(r[4], r[5]), add_rn(r[6], r[7])));
    }
    return add_rn(blk[0], blk[1]);
}

// ------------------------------------------------ K1a: c_sq (np-exact sum)
__global__ __launch_bounds__(256)
void csq_kernel(const float* __restrict__ cb, float* __restrict__ csq) {
    int k = blockIdx.x * 256 + threadIdx.x;       // one thread per code
    if (k >= K) return;
    const float* row = cb + (size_t)k * D;
    csq[k] = np_sumsq_256([&](int d) { return row[d]; });
}

// ------------------------------------------------ K1b: x_sq (np-exact sum)
// flat[n][d] = x[b][d][h][w], n = b*1024 + hw  -> stride BHW between d's
__global__ __launch_bounds__(256)
void xsq_kernel(const float* __restrict__ x, float* __restrict__ xsq) {
    int n = blockIdx.x * 256 + threadIdx.x;       // one thread per row
    if (n >= NROWS) return;
    int b = n >> 10, hw = n & 1023;
    const float* p = x + (size_t)b * (D * BHW) + hw;
    xsq[n] = np_sumsq_256([&](int d) { return p[(size_t)d * BHW]; });
}

// ------------------------------------------- K2: fp32 GEMM + running argmin
// dist[n][k] = fl( fl(xsq[n] + csq[k]) - 2*dot(x[n], cb[k]) )  -- f32 buckets
__global__ __launch_bounds__(256)
void gemm_argmin_kernel(const float* __restrict__ x,    // [16][256][32][32]
                        const float* __restrict__ cb,   // [8192][256]
                        const float* __restrict__ csq,  // [8192]
                        const float* __restrict__ xsq,  // [16384]
                        float* __restrict__ pmin,       // [NROWS][KPART]
                        int*   __restrict__ pidx) {
    __shared__ __align__(16) float xT[DC * LSTR];   // [d][n] transposed
    __shared__ __align__(16) float cT[DC * LSTR];   // [d][k] transposed
    __shared__ float rs[TM * 16];
    __shared__ int   ri[TM * 16];

    const int tid = threadIdx.x;
    const int tx  = tid & 15;        // k-tile coord (8 codes)
    const int ty  = tid >> 4;        // n-tile coord (8 rows)
    const int nb  = blockIdx.x;      // 0..127
    const int kp  = blockIdx.y;      // 0..3

    const int rowBase = nb * TM;
    const int b   = nb >> 3;                 // 128 rows stay within one batch
    const int hw0 = (nb & 7) * TM;
    const float* xb = x + (size_t)b * (D * BHW) + hw0;

    float rmin[8];
    int   ridx[8];
    float xsqv[8];
    #pragma unroll
    for (int i = 0; i < 8; ++i) {
        rmin[i] = FLT_MAX; ridx[i] = 0;
        xsqv[i] = xsq[rowBase + ty * 8 + i];
    }

    const int dd  = tid >> 5;   // 0..7  (x loader)
    const int nn4 = tid & 31;   // 0..31
    const int kk  = tid >> 3;   // 0..31 (c loader)
    const int dq  = tid & 7;    // 0..7

    const float4* xT4 = (const float4*)xT;
    const float4* cT4 = (const float4*)cT;

    for (int kc = 0; kc < KSLICE / TK; ++kc) {          // 16 k-chunks
        const int kbase = kp * KSLICE + kc * TK;
        float acc[64];
        #pragma unroll
        for (int i = 0; i < 64; ++i) acc[i] = 0.f;

        for (int dc = 0; dc < D / DC; ++dc) {           // 8 d-stages
            const int dbase = dc * DC;
            // stage x transposed: xT[d][n]  (coalesced along n)
            #pragma unroll
            for (int r = 0; r < 4; ++r) {
                const int drow = dd + 8 * r;
                float4 v = *(const float4*)(xb + (size_t)(dbase + drow) * BHW + nn4 * 4);
                *(float4*)(&xT[drow * LSTR + nn4 * 4]) = v;
            }
            // stage codebook transposed: cT[d][k]
            #pragma unroll
            for (int r = 0; r < 4; ++r) {
                const int krow = kbase + kk + 32 * r;
                float4 v = *(const float4*)(cb + (size_t)krow * D + dbase + dq * 4);
                cT[(dq * 4 + 0) * LSTR + kk + 32 * r] = v.x;
                cT[(dq * 4 + 1) * LSTR + kk + 32 * r] = v.y;
                cT[(dq * 4 + 2) * LSTR + kk + 32 * r] = v.z;
                cT[(dq * 4 + 3) * LSTR + kk + 32 * r] = v.w;
            }
            __syncthreads();
            #pragma unroll
            for (int d = 0; d < DC; ++d) {
                float4 a0 = xT4[d * (LSTR / 4) + ty * 2];
                float4 a1 = xT4[d * (LSTR / 4) + ty * 2 + 1];
                float4 b0 = cT4[d * (LSTR / 4) + tx * 2];
                float4 b1 = cT4[d * (LSTR / 4) + tx * 2 + 1];
                float xv[8] = {a0.x, a0.y, a0.z, a0.w, a1.x, a1.y, a1.z, a1.w};
                float cv[8] = {b0.x, b0.y, b0.z, b0.w, b1.x, b1.y, b1.z, b1.w};
                #pragma unroll
                for (int i = 0; i < 8; ++i)
                    #pragma unroll
                    for (int j = 0; j < 8; ++j)
                        acc[i * 8 + j] = fmaf(xv[i], cv[j], acc[i * 8 + j]);
            }
            __syncthreads();
        }
        // fold: dist = fl(fl(xsq+csq) - 2*acc), replicate np's f32 rounding.
        // k strictly increasing per thread; strict '<' keeps earliest index.
        float4 q0 = *(const float4*)(csq + kbase + tx * 8);
        float4 q1 = *(const float4*)(csq + kbase + tx * 8 + 4);
        float qv[8] = {q0.x, q0.y, q0.z, q0.w, q1.x, q1.y, q1.z, q1.w};
        #pragma unroll
        for (int j = 0; j < 8; ++j) {
            const int kg = kbase + tx * 8 + j;
            #pragma unroll
            for (int i = 0; i < 8; ++i) {
                float t1 = add_rn(xsqv[i], qv[j]);
                float s  = sub_rn(t1, mul_rn(2.0f, acc[i * 8 + j]));
                if (s < rmin[i]) { rmin[i] = s; ridx[i] = kg; }
            }
        }
    }
    // cross-tx reduction per row (tie -> smaller index)
    __syncthreads();
    #pragma unroll
    for (int i = 0; i < 8; ++i) {
        rs[(ty * 8 + i) * 16 + tx] = rmin[i];
        ri[(ty * 8 + i) * 16 + tx] = ridx[i];
    }
    __syncthreads();
    if (tid < TM) {
        float best = rs[tid * 16];
        int   bi   = ri[tid * 16];
        #pragma unroll
        for (int t = 1; t < 16; ++t) {
            float s  = rs[tid * 16 + t];
            int   id = ri[tid * 16 + t];
            if (s < best || (s == best && id < bi)) { best = s; bi = id; }
        }
        const int n = rowBase + tid;
        pmin[n * KPART + kp] = best;
        pidx[n * KPART + kp] = bi;
    }
}

// ----------------------------------------------- K3: reduce KPART partials
__global__ __launch_bounds__(256)
void reduce_argmin_kernel(const float* __restrict__ pmin, const int* __restrict__ pidx,
                          int* __restrict__ idx) {
    int n = blockIdx.x * 256 + threadIdx.x;
    if (n >= NROWS) return;
    float best = pmin[n * KPART];
    int   bi   = pidx[n * KPART];
    #pragma unroll
    for (int p = 1; p < KPART; ++p) {
        float s  = pmin[n * KPART + p];
        int   id = pidx[n * KPART + p];
        if (s < best || (s == best && id < bi)) { best = s; bi = id; }
    }
    idx[n] = bi;
}

// -------------------------------- K4: quantized gather back to (B,C,H,W)
__global__ __launch_bounds__(256)
void gather_quant_kernel(const float* __restrict__ cb, const int* __restrict__ idx,
                         float* __restrict__ out0) {
    int t = blockIdx.x * 256 + threadIdx.x;        // one float4 of output
    int hw4 = t & 255;
    int d   = (t >> 8) & 255;
    int b   = t >> 16;
    int n0  = b * BHW + hw4 * 4;
    float4 o;
    o.x = cb[(size_t)idx[n0 + 0] * D + d];
    o.y = cb[(size_t)idx[n0 + 1] * D + d];
    o.z = cb[(size_t)idx[n0 + 2] * D + d];
    o.w = cb[(size_t)idx[n0 + 3] * D + d];
    ((float4*)out0)[t] = o;
}

// ------------------------------------------------------- K5: one-hot fill
__global__ __launch_bounds__(256)
void onehot_kernel(const int* __restrict__ idx, float* __restrict__ out1) {
    int t = blockIdx.x * 256 + threadIdx.x;        // one float4 of one_hot
    int n  = t >> 11;                              // 2048 float4 per row
    int k0 = (t & 2047) * 4;
    int target = idx[n];
    float4 v = {0.f, 0.f, 0.f, 0.f};
    int r = target - k0;
    if (r >= 0 && r < 4) ((float*)&v)[r] = 1.0f;
    ((float4*)out1)[t] = v;
}

// ------------------------------------------------------------------ launch
extern "C" void kernel_launch(void* const* d_in, const int* in_sizes, int n_in,
                              void* d_out, int out_size, void* d_ws, size_t ws_size,
                              hipStream_t stream) {
    const float* x  = (const float*)d_in[0];   // [16][256][32][32]
    const float* cb = (const float*)d_in[1];   // [8192][256]
    float* out0 = (float*)d_out;                       // quantized: 4,194,304 floats
    float* out1 = (float*)d_out + 4194304;             // one_hot:  134,217,728 floats

    // workspace layout (all regions written before read each launch)
    char* ws = (char*)d_ws;
    float* csq  = (float*)(ws + 0);           //  8192 floats   (32 KB)
    float* xsq  = (float*)(ws + 32768);       // 16384 floats   (64 KB)
    int*   idx  = (int*)  (ws + 98304);       // 16384 ints     (64 KB)
    float* pmin = (float*)(ws + 163840);      // 16384*4 floats (256 KB)
    int*   pidx = (int*)  (ws + 425984);      // 16384*4 ints   (256 KB)

    csq_kernel<<<K / 256, 256, 0, stream>>>(cb, csq);
    xsq_kernel<<<NROWS / 256, 256, 0, stream>>>(x, xsq);

    dim3 ggrid(NROWS / TM, KPART);
    gemm_argmin_kernel<<<ggrid, 256, 0, stream>>>(x, cb, csq, xsq, pmin, pidx);

    reduce_argmin_kernel<<<NROWS / 256, 256, 0, stream>>>(pmin, pidx, idx);

    gather_quant_kernel<<<(4194304 / 4) / 256, 256, 0, stream>>>(cb, idx, out0);

    onehot_kernel<<<(134217728 / 4) / 256, 256, 0, stream>>>(idx, out1);
}

// Round 3
// 1351.445 us; speedup vs baseline: 1.0398x; 1.0398x over previous
//
#include <hip/hip_runtime.h>
#include <float.h>

// Problem constants
constexpr int D      = 256;     // code dim
constexpr int K      = 8192;    // n codes
constexpr int NROWS  = 16384;   // 16 * 32 * 32
constexpr int BHW    = 1024;    // 32*32 spatial per batch

// GEMM tiling
constexpr int TM    = 128;            // rows per block
constexpr int TK    = 128;            // codes per k-chunk
constexpr int DC    = 32;             // d per LDS stage
constexpr int KPART = 8;              // k splits (grid.y)
constexpr int KSLICE = K / KPART;     // 1024
constexpr int LSTR  = 128;            // LDS row stride (floats), no pad needed

// ---- contraction-proof f32 ops (must round exactly like numpy's elementwise)
__device__ __forceinline__ float mul_rn(float a, float b) {
#pragma clang fp contract(off)
    return a * b;
}
__device__ __forceinline__ float add_rn(float a, float b) {
#pragma clang fp contract(off)
    return a + b;
}
__device__ __forceinline__ float sub_rn(float a, float b) {
#pragma clang fp contract(off)
    return a - b;
}

// numpy pairwise_sum replica for 256 f32 squares (8 chains stride 8, tree merge)
template <typename LOAD>
__device__ __forceinline__ float np_sumsq_256(LOAD ld) {
    float blk[2];
    #pragma unroll
    for (int h = 0; h < 2; ++h) {
        const int base = h * 128;
        float r[8];
        #pragma unroll
        for (int j = 0; j < 8; ++j) {
            float v = ld(base + j);
            r[j] = mul_rn(v, v);
        }
        for (int i = 8; i < 128; i += 8) {
            #pragma unroll
            for (int j = 0; j < 8; ++j) {
                float v = ld(base + i + j);
                r[j] = add_rn(r[j], mul_rn(v, v));
            }
        }
        blk[h] = add_rn(add_rn(add_rn(r[0], r[1]), add_rn(r[2], r[3])),
                        add_rn(add_rn(r[4], r[5]), add_rn(r[6], r[7])));
    }
    return add_rn(blk[0], blk[1]);
}

// ------------------------------------- K0: transpose cb[8192][256] -> cbT[256][8192]
__global__ __launch_bounds__(256)
void transpose_cb_kernel(const float* __restrict__ cb, float* __restrict__ cbT) {
    __shared__ float t[32][33];
    const int tid = threadIdx.x;
    const int tx  = tid & 31;        // fast dim within tile
    const int ty  = tid >> 5;        // 0..7
    const int k0  = (blockIdx.x & 255) * 32;   // 256 k-tiles
    const int d0  = (blockIdx.x >> 8) * 32;    // 8 d-tiles
    #pragma unroll
    for (int r = 0; r < 4; ++r)
        t[ty + 8 * r][tx] = cb[(size_t)(k0 + ty + 8 * r) * D + d0 + tx];
    __syncthreads();
    #pragma unroll
    for (int r = 0; r < 4; ++r)
        cbT[(size_t)(d0 + ty + 8 * r) * K + k0 + tx] = t[tx][ty + 8 * r];
}

// ------------------------------------------------ K1a: c_sq (np-exact sum)
__global__ __launch_bounds__(256)
void csq_kernel(const float* __restrict__ cb, float* __restrict__ csq) {
    int k = blockIdx.x * 256 + threadIdx.x;
    if (k >= K) return;
    const float* row = cb + (size_t)k * D;
    csq[k] = np_sumsq_256([&](int d) { return row[d]; });
}

// ------------------------------------------------ K1b: x_sq (np-exact sum)
__global__ __launch_bounds__(256)
void xsq_kernel(const float* __restrict__ x, float* __restrict__ xsq) {
    int n = blockIdx.x * 256 + threadIdx.x;
    if (n >= NROWS) return;
    int b = n >> 10, hw = n & 1023;
    const float* p = x + (size_t)b * (D * BHW) + hw;
    xsq[n] = np_sumsq_256([&](int d) { return p[(size_t)d * BHW]; });
}

// ------------------------------------------- K2: fp32 GEMM + running argmin
// dist[n][k] = fl( fl(xsq[n] + csq[k]) - 2*dot(x[n], cb[k]) )  -- f32 buckets
__global__ __launch_bounds__(256)
void gemm_argmin_kernel(const float* __restrict__ x,    // [16][256][32][32]
                        const float* __restrict__ cbT,  // [256][8192]
                        const float* __restrict__ csq,  // [8192]
                        const float* __restrict__ xsq,  // [16384]
                        float* __restrict__ pmin,       // [NROWS][KPART]
                        int*   __restrict__ pidx) {
    __shared__ __align__(16) char smem_raw[2 * DC * LSTR * 4];   // 32 KB
    float* xT = (float*)smem_raw;                    // [DC][128]
    float* cT = (float*)(smem_raw + DC * LSTR * 4);  // [DC][128]
    float* rs = (float*)smem_raw;                    // overlay (epilogue)
    int*   ri = (int*)(smem_raw + TM * 16 * 4);

    const int tid = threadIdx.x;
    const int tx  = tid & 15;        // k-tile coord (8 codes)
    const int ty  = tid >> 4;        // n-tile coord (8 rows)
    const int nb  = blockIdx.x;      // 0..127
    const int kp  = blockIdx.y;      // 0..KPART-1

    const int rowBase = nb * TM;
    const int b   = nb >> 3;                 // 128 rows stay within one batch
    const int hw0 = (nb & 7) * TM;
    const float* xb = x + (size_t)b * (D * BHW) + hw0;

    float rmin[8];
    int   ridx[8];
    float xsqv[8];
    #pragma unroll
    for (int i = 0; i < 8; ++i) {
        rmin[i] = FLT_MAX; ridx[i] = 0;
        xsqv[i] = xsq[rowBase + ty * 8 + i];
    }

    const int dd  = tid >> 5;   // 0..7  (loader d)
    const int nn4 = tid & 31;   // 0..31 (loader fast dim, float4)

    const float4* xT4 = (const float4*)xT;
    const float4* cT4 = (const float4*)cT;

    for (int kc = 0; kc < KSLICE / TK; ++kc) {          // 8 k-chunks
        const int kbase = kp * KSLICE + kc * TK;
        float acc[64];
        #pragma unroll
        for (int i = 0; i < 64; ++i) acc[i] = 0.f;

        for (int dc = 0; dc < D / DC; ++dc) {           // 8 d-stages
            const int dbase = dc * DC;
            // stage x transposed tile: xT[d][n] (coalesced, b128 writes sweep n)
            #pragma unroll
            for (int r = 0; r < 4; ++r) {
                const int drow = dd + 8 * r;
                float4 v = *(const float4*)(xb + (size_t)(dbase + drow) * BHW + nn4 * 4);
                *(float4*)(&xT[drow * LSTR + nn4 * 4]) = v;
            }
            // stage codebook tile from cbT: cT[d][k] (coalesced, b128 writes sweep k)
            #pragma unroll
            for (int r = 0; r < 4; ++r) {
                const int drow = dd + 8 * r;
                float4 v = *(const float4*)(cbT + (size_t)(dbase + drow) * K + kbase + nn4 * 4);
                *(float4*)(&cT[drow * LSTR + nn4 * 4]) = v;
            }
            __syncthreads();
            #pragma unroll
            for (int d = 0; d < DC; ++d) {
                float4 a0 = xT4[d * (LSTR / 4) + ty * 2];
                float4 a1 = xT4[d * (LSTR / 4) + ty * 2 + 1];
                float4 b0 = cT4[d * (LSTR / 4) + tx * 2];
                float4 b1 = cT4[d * (LSTR / 4) + tx * 2 + 1];
                float xv[8] = {a0.x, a0.y, a0.z, a0.w, a1.x, a1.y, a1.z, a1.w};
                float cv[8] = {b0.x, b0.y, b0.z, b0.w, b1.x, b1.y, b1.z, b1.w};
                #pragma unroll
                for (int i = 0; i < 8; ++i)
                    #pragma unroll
                    for (int j = 0; j < 8; ++j)
                        acc[i * 8 + j] = fmaf(xv[i], cv[j], acc[i * 8 + j]);
            }
            __syncthreads();
        }
        // fold: dist = fl(fl(xsq+csq) - 2*acc), replicate np's f32 rounding.
        float4 q0 = *(const float4*)(csq + kbase + tx * 8);
        float4 q1 = *(const float4*)(csq + kbase + tx * 8 + 4);
        float qv[8] = {q0.x, q0.y, q0.z, q0.w, q1.x, q1.y, q1.z, q1.w};
        #pragma unroll
        for (int j = 0; j < 8; ++j) {
            const int kg = kbase + tx * 8 + j;
            #pragma unroll
            for (int i = 0; i < 8; ++i) {
                float t1 = add_rn(xsqv[i], qv[j]);
                float s  = sub_rn(t1, mul_rn(2.0f, acc[i * 8 + j]));
                if (s < rmin[i]) { rmin[i] = s; ridx[i] = kg; }
            }
        }
    }
    // cross-tx reduction per row (tie -> smaller index); rs/ri overlay tiles
    __syncthreads();
    #pragma unroll
    for (int i = 0; i < 8; ++i) {
        rs[(ty * 8 + i) * 16 + tx] = rmin[i];
        ri[(ty * 8 + i) * 16 + tx] = ridx[i];
    }
    __syncthreads();
    if (tid < TM) {
        float best = rs[tid * 16];
        int   bi   = ri[tid * 16];
        #pragma unroll
        for (int t = 1; t < 16; ++t) {
            float s  = rs[tid * 16 + t];
            int   id = ri[tid * 16 + t];
            if (s < best || (s == best && id < bi)) { best = s; bi = id; }
        }
        const int n = rowBase + tid;
        pmin[n * KPART + kp] = best;
        pidx[n * KPART + kp] = bi;
    }
}

// ----------------------------------------------- K3: reduce KPART partials
__global__ __launch_bounds__(256)
void reduce_argmin_kernel(const float* __restrict__ pmin, const int* __restrict__ pidx,
                          int* __restrict__ idx) {
    int n = blockIdx.x * 256 + threadIdx.x;
    if (n >= NROWS) return;
    float best = pmin[n * KPART];
    int   bi   = pidx[n * KPART];
    #pragma unroll
    for (int p = 1; p < KPART; ++p) {
        float s  = pmin[n * KPART + p];
        int   id = pidx[n * KPART + p];
        if (s < best || (s == best && id < bi)) { best = s; bi = id; }
    }
    idx[n] = bi;
}

// -------------------------------- K4: quantized gather back to (B,C,H,W)
__global__ __launch_bounds__(256)
void gather_quant_kernel(const float* __restrict__ cb, const int* __restrict__ idx,
                         float* __restrict__ out0) {
    int t = blockIdx.x * 256 + threadIdx.x;        // one float4 of output
    int hw4 = t & 255;
    int d   = (t >> 8) & 255;
    int b   = t >> 16;
    int n0  = b * BHW + hw4 * 4;
    float4 o;
    o.x = cb[(size_t)idx[n0 + 0] * D + d];
    o.y = cb[(size_t)idx[n0 + 1] * D + d];
    o.z = cb[(size_t)idx[n0 + 2] * D + d];
    o.w = cb[(size_t)idx[n0 + 3] * D + d];
    ((float4*)out0)[t] = o;
}

// ------------------------------------------------------- K5: one-hot fill
__global__ __launch_bounds__(256)
void onehot_kernel(const int* __restrict__ idx, float* __restrict__ out1) {
    int t = blockIdx.x * 256 + threadIdx.x;        // one float4 of one_hot
    int n  = t >> 11;                              // 2048 float4 per row
    int k0 = (t & 2047) * 4;
    int target = idx[n];
    float4 v = {0.f, 0.f, 0.f, 0.f};
    int r = target - k0;
    if (r >= 0 && r < 4) ((float*)&v)[r] = 1.0f;
    ((float4*)out1)[t] = v;
}

// ------------------------------------------------------------------ launch
extern "C" void kernel_launch(void* const* d_in, const int* in_sizes, int n_in,
                              void* d_out, int out_size, void* d_ws, size_t ws_size,
                              hipStream_t stream) {
    const float* x  = (const float*)d_in[0];   // [16][256][32][32]
    const float* cb = (const float*)d_in[1];   // [8192][256]
    float* out0 = (float*)d_out;                       // quantized: 4,194,304 floats
    float* out1 = (float*)d_out + 4194304;             // one_hot:  134,217,728 floats

    // small scratch in ws (proven size); big scratch lives in the one_hot
    // output region, which is only written (overwritten) by the final kernel.
    char* ws = (char*)d_ws;
    float* csq  = (float*)(ws + 0);           //  8192 floats (32 KB)
    float* xsq  = (float*)(ws + 32768);       // 16384 floats (64 KB)
    int*   idx  = (int*)  (ws + 98304);       // 16384 ints   (64 KB)

    float* cbT  = out1;                        // 2,097,152 floats (8 MB)
    float* pmin = out1 + 2097152;              // NROWS*KPART floats (512 KB)
    int*   pidx = (int*)(out1 + 2097152 + NROWS * KPART);  // 512 KB

    transpose_cb_kernel<<<2048, 256, 0, stream>>>(cb, cbT);
    csq_kernel<<<K / 256, 256, 0, stream>>>(cb, csq);
    xsq_kernel<<<NROWS / 256, 256, 0, stream>>>(x, xsq);

    dim3 ggrid(NROWS / TM, KPART);
    gemm_argmin_kernel<<<ggrid, 256, 0, stream>>>(x, cbT, csq, xsq, pmin, pidx);

    reduce_argmin_kernel<<<NROWS / 256, 256, 0, stream>>>(pmin, pidx, idx);

    gather_quant_kernel<<<(4194304 / 4) / 256, 256, 0, stream>>>(cb, idx, out0);

    onehot_kernel<<<(134217728 / 4) / 256, 256, 0, stream>>>(idx, out1);
}

// Round 4
// 1341.481 us; speedup vs baseline: 1.0475x; 1.0074x over previous
//
#include <hip/hip_runtime.h>
#include <float.h>

// Problem constants
constexpr int D      = 256;     // code dim
constexpr int K      = 8192;    // n codes
constexpr int NROWS  = 16384;   // 16 * 32 * 32
constexpr int BHW    = 1024;    // 32*32 spatial per batch

// GEMM tiling
constexpr int TM    = 128;            // rows per block
constexpr int TK    = 128;            // codes per k-chunk
constexpr int DC    = 32;             // d per LDS stage
constexpr int KPART = 16;             // k splits (grid.y) -> 2048 blocks
constexpr int KSLICE = K / KPART;     // 512
constexpr int LSTR  = 128;            // LDS row stride (floats)

// ---- contraction-proof f32 ops (must round exactly like numpy's elementwise)
__device__ __forceinline__ float mul_rn(float a, float b) {
#pragma clang fp contract(off)
    return a * b;
}
__device__ __forceinline__ float add_rn(float a, float b) {
#pragma clang fp contract(off)
    return a + b;
}
__device__ __forceinline__ float sub_rn(float a, float b) {
#pragma clang fp contract(off)
    return a - b;
}

// numpy pairwise_sum replica for 256 f32 squares (8 chains stride 8, tree merge)
template <typename LOAD>
__device__ __forceinline__ float np_sumsq_256(LOAD ld) {
    float blk[2];
    #pragma unroll
    for (int h = 0; h < 2; ++h) {
        const int base = h * 128;
        float r[8];
        #pragma unroll
        for (int j = 0; j < 8; ++j) {
            float v = ld(base + j);
            r[j] = mul_rn(v, v);
        }
        for (int i = 8; i < 128; i += 8) {
            #pragma unroll
            for (int j = 0; j < 8; ++j) {
                float v = ld(base + i + j);
                r[j] = add_rn(r[j], mul_rn(v, v));
            }
        }
        blk[h] = add_rn(add_rn(add_rn(r[0], r[1]), add_rn(r[2], r[3])),
                        add_rn(add_rn(r[4], r[5]), add_rn(r[6], r[7])));
    }
    return add_rn(blk[0], blk[1]);
}

// ------------------------------------- K0: transpose cb[8192][256] -> cbT[256][8192]
__global__ __launch_bounds__(256)
void transpose_cb_kernel(const float* __restrict__ cb, float* __restrict__ cbT) {
    __shared__ float t[32][33];
    const int tid = threadIdx.x;
    const int tx  = tid & 31;        // fast dim within tile
    const int ty  = tid >> 5;        // 0..7
    const int k0  = (blockIdx.x & 255) * 32;   // 256 k-tiles
    const int d0  = (blockIdx.x >> 8) * 32;    // 8 d-tiles
    #pragma unroll
    for (int r = 0; r < 4; ++r)
        t[ty + 8 * r][tx] = cb[(size_t)(k0 + ty + 8 * r) * D + d0 + tx];
    __syncthreads();
    #pragma unroll
    for (int r = 0; r < 4; ++r)
        cbT[(size_t)(d0 + ty + 8 * r) * K + k0 + tx] = t[tx][ty + 8 * r];
}

// ------------------------------------------------ K1a: c_sq (np-exact sum)
__global__ __launch_bounds__(256)
void csq_kernel(const float* __restrict__ cb, float* __restrict__ csq) {
    int k = blockIdx.x * 256 + threadIdx.x;
    if (k >= K) return;
    const float* row = cb + (size_t)k * D;
    csq[k] = np_sumsq_256([&](int d) { return row[d]; });
}

// ------------------------------------------------ K1b: x_sq (np-exact sum)
__global__ __launch_bounds__(256)
void xsq_kernel(const float* __restrict__ x, float* __restrict__ xsq) {
    int n = blockIdx.x * 256 + threadIdx.x;
    if (n >= NROWS) return;
    int b = n >> 10, hw = n & 1023;
    const float* p = x + (size_t)b * (D * BHW) + hw;
    xsq[n] = np_sumsq_256([&](int d) { return p[(size_t)d * BHW]; });
}

// ------------------------------------------- K2: fp32 GEMM + running argmin
// dist[n][k] = fl( fl(xsq[n] + csq[k]) - 2*dot(x[n], cb[k]) )  -- f32 buckets
__global__ __launch_bounds__(256)
void gemm_argmin_kernel(const float* __restrict__ x,    // [16][256][32][32]
                        const float* __restrict__ cbT,  // [256][8192]
                        const float* __restrict__ csq,  // [8192]
                        const float* __restrict__ xsq,  // [16384]
                        float* __restrict__ pmin,       // [NROWS][KPART]
                        int*   __restrict__ pidx) {
    __shared__ __align__(16) char smem_raw[2 * DC * LSTR * 4];   // 32 KB
    float* xT = (float*)smem_raw;                    // [DC][128]
    float* cT = (float*)(smem_raw + DC * LSTR * 4);  // [DC][128]
    float* rs = (float*)smem_raw;                    // overlay (epilogue)
    int*   ri = (int*)(smem_raw + TM * 16 * 4);

    const int tid = threadIdx.x;
    const int tx  = tid & 15;        // k-tile coord
    const int ty  = tid >> 4;        // n-tile coord (8 rows)
    const int nb  = blockIdx.x;      // 0..127
    const int kp  = blockIdx.y;      // 0..KPART-1

    const int rowBase = nb * TM;
    const int b   = nb >> 3;                 // 128 rows stay within one batch
    const int hw0 = (nb & 7) * TM;
    const float* xb = x + (size_t)b * (D * BHW) + hw0;

    float rmin[8];
    int   ridx[8];
    float xsqv[8];
    #pragma unroll
    for (int i = 0; i < 8; ++i) {
        rmin[i] = FLT_MAX; ridx[i] = 0;
        xsqv[i] = xsq[rowBase + ty * 8 + i];
    }

    const int dd  = tid >> 5;   // 0..7  (loader d)
    const int nn4 = tid & 31;   // 0..31 (loader fast dim, float4)

    const float4* xT4 = (const float4*)xT;
    const float4* cT4 = (const float4*)cT;

    for (int kc = 0; kc < KSLICE / TK; ++kc) {          // 4 k-chunks
        const int kbase = kp * KSLICE + kc * TK;
        float acc[64];
        #pragma unroll
        for (int i = 0; i < 64; ++i) acc[i] = 0.f;

        for (int dc = 0; dc < D / DC; ++dc) {           // 8 d-stages
            const int dbase = dc * DC;
            // stage x transposed tile: xT[d][n] (coalesced, b128 writes sweep n)
            #pragma unroll
            for (int r = 0; r < 4; ++r) {
                const int drow = dd + 8 * r;
                float4 v = *(const float4*)(xb + (size_t)(dbase + drow) * BHW + nn4 * 4);
                *(float4*)(&xT[drow * LSTR + nn4 * 4]) = v;
            }
            // stage codebook tile from cbT: cT[d][k] (coalesced, b128 writes sweep k)
            #pragma unroll
            for (int r = 0; r < 4; ++r) {
                const int drow = dd + 8 * r;
                float4 v = *(const float4*)(cbT + (size_t)(dbase + drow) * K + kbase + nn4 * 4);
                *(float4*)(&cT[drow * LSTR + nn4 * 4]) = v;
            }
            __syncthreads();
            #pragma unroll
            for (int d = 0; d < DC; ++d) {
                // a-reads: 4 distinct 16B addrs/wave (banks disjoint) - conflict-free
                float4 a0 = xT4[d * (LSTR / 4) + ty * 2];
                float4 a1 = xT4[d * (LSTR / 4) + ty * 2 + 1];
                // b-reads: 16 distinct addrs at 16B stride spanning 256B ->
                // exactly 2 addrs/bank = free (was 32B stride = 4-way conflict)
                float4 b0 = cT4[d * (LSTR / 4) + tx];
                float4 b1 = cT4[d * (LSTR / 4) + 16 + tx];
                float xv[8] = {a0.x, a0.y, a0.z, a0.w, a1.x, a1.y, a1.z, a1.w};
                float cv[8] = {b0.x, b0.y, b0.z, b0.w, b1.x, b1.y, b1.z, b1.w};
                #pragma unroll
                for (int i = 0; i < 8; ++i)
                    #pragma unroll
                    for (int j = 0; j < 8; ++j)
                        acc[i * 8 + j] = fmaf(xv[i], cv[j], acc[i * 8 + j]);
            }
            __syncthreads();
        }
        // fold: dist = fl(fl(xsq+csq) - 2*acc), replicate np's f32 rounding.
        // thread's codes: {tx*4+0..3} and {64+tx*4+0..3} (k strictly increasing)
        float4 q0 = *(const float4*)(csq + kbase + tx * 4);
        float4 q1 = *(const float4*)(csq + kbase + 64 + tx * 4);
        float qv[8] = {q0.x, q0.y, q0.z, q0.w, q1.x, q1.y, q1.z, q1.w};
        #pragma unroll
        for (int j = 0; j < 8; ++j) {
            const int kg = kbase + (j < 4 ? tx * 4 + j : 64 + tx * 4 + (j - 4));
            #pragma unroll
            for (int i = 0; i < 8; ++i) {
                float t1 = add_rn(xsqv[i], qv[j]);
                float s  = sub_rn(t1, mul_rn(2.0f, acc[i * 8 + j]));
                if (s < rmin[i]) { rmin[i] = s; ridx[i] = kg; }
            }
        }
    }
    // cross-tx reduction per row (tie -> smaller index); rs/ri overlay tiles
    __syncthreads();
    #pragma unroll
    for (int i = 0; i < 8; ++i) {
        rs[(ty * 8 + i) * 16 + tx] = rmin[i];
        ri[(ty * 8 + i) * 16 + tx] = ridx[i];
    }
    __syncthreads();
    if (tid < TM) {
        float best = rs[tid * 16];
        int   bi   = ri[tid * 16];
        #pragma unroll
        for (int t = 1; t < 16; ++t) {
            float s  = rs[tid * 16 + t];
            int   id = ri[tid * 16 + t];
            if (s < best || (s == best && id < bi)) { best = s; bi = id; }
        }
        const int n = rowBase + tid;
        pmin[n * KPART + kp] = best;
        pidx[n * KPART + kp] = bi;
    }
}

// ----------------------------------------------- K3: reduce KPART partials
__global__ __launch_bounds__(256)
void reduce_argmin_kernel(const float* __restrict__ pmin, const int* __restrict__ pidx,
                          int* __restrict__ idx) {
    int n = blockIdx.x * 256 + threadIdx.x;
    if (n >= NROWS) return;
    float best = pmin[n * KPART];
    int   bi   = pidx[n * KPART];
    #pragma unroll
    for (int p = 1; p < KPART; ++p) {
        float s  = pmin[n * KPART + p];
        int   id = pidx[n * KPART + p];
        if (s < best || (s == best && id < bi)) { best = s; bi = id; }
    }
    idx[n] = bi;
}

// -------------------------------- K4: quantized gather back to (B,C,H,W)
__global__ __launch_bounds__(256)
void gather_quant_kernel(const float* __restrict__ cb, const int* __restrict__ idx,
                         float* __restrict__ out0) {
    int t = blockIdx.x * 256 + threadIdx.x;        // one float4 of output
    int hw4 = t & 255;
    int d   = (t >> 8) & 255;
    int b   = t >> 16;
    int n0  = b * BHW + hw4 * 4;
    float4 o;
    o.x = cb[(size_t)idx[n0 + 0] * D + d];
    o.y = cb[(size_t)idx[n0 + 1] * D + d];
    o.z = cb[(size_t)idx[n0 + 2] * D + d];
    o.w = cb[(size_t)idx[n0 + 3] * D + d];
    ((float4*)out0)[t] = o;
}

// ------------------------------------------------------- K5: one-hot fill
__global__ __launch_bounds__(256)
void onehot_kernel(const int* __restrict__ idx, float* __restrict__ out1) {
    int t = blockIdx.x * 256 + threadIdx.x;        // one float4 of one_hot
    int n  = t >> 11;                              // 2048 float4 per row
    int k0 = (t & 2047) * 4;
    int target = idx[n];
    float4 v = {0.f, 0.f, 0.f, 0.f};
    int r = target - k0;
    if (r >= 0 && r < 4) ((float*)&v)[r] = 1.0f;
    ((float4*)out1)[t] = v;
}

// ------------------------------------------------------------------ launch
extern "C" void kernel_launch(void* const* d_in, const int* in_sizes, int n_in,
                              void* d_out, int out_size, void* d_ws, size_t ws_size,
                              hipStream_t stream) {
    const float* x  = (const float*)d_in[0];   // [16][256][32][32]
    const float* cb = (const float*)d_in[1];   // [8192][256]
    float* out0 = (float*)d_out;                       // quantized: 4,194,304 floats
    float* out1 = (float*)d_out + 4194304;             // one_hot:  134,217,728 floats

    // small scratch in ws; big scratch lives in the one_hot output region,
    // which is fully overwritten by the final kernel.
    char* ws = (char*)d_ws;
    float* csq  = (float*)(ws + 0);           //  8192 floats (32 KB)
    float* xsq  = (float*)(ws + 32768);       // 16384 floats (64 KB)
    int*   idx  = (int*)  (ws + 98304);       // 16384 ints   (64 KB)

    float* cbT  = out1;                        // 2,097,152 floats (8 MB)
    float* pmin = out1 + 2097152;              // NROWS*KPART floats (1 MB)
    int*   pidx = (int*)(out1 + 2097152 + NROWS * KPART);  // 1 MB

    transpose_cb_kernel<<<2048, 256, 0, stream>>>(cb, cbT);
    csq_kernel<<<K / 256, 256, 0, stream>>>(cb, csq);
    xsq_kernel<<<NROWS / 256, 256, 0, stream>>>(x, xsq);

    dim3 ggrid(NROWS / TM, KPART);
    gemm_argmin_kernel<<<ggrid, 256, 0, stream>>>(x, cbT, csq, xsq, pmin, pidx);

    reduce_argmin_kernel<<<NROWS / 256, 256, 0, stream>>>(pmin, pidx, idx);

    gather_quant_kernel<<<(4194304 / 4) / 256, 256, 0, stream>>>(cb, idx, out0);

    onehot_kernel<<<(134217728 / 4) / 256, 256, 0, stream>>>(idx, out1);
}

// Round 5
// 1251.098 us; speedup vs baseline: 1.1232x; 1.0722x over previous
//
#include <hip/hip_runtime.h>
#include <float.h>
#include <stdint.h>

// Problem constants
constexpr int D      = 256;     // code dim
constexpr int K      = 8192;    // n codes
constexpr int NROWS  = 16384;   // 16 * 32 * 32
constexpr int BHW    = 1024;    // 32*32 spatial per batch
constexpr int KS     = 768;     // split-K for screen gemm (hi|lo|hi)
constexpr float MARGIN = 2e-4f; // screen margin >> 9.8e-5 error bound

typedef __bf16 bf16x8 __attribute__((ext_vector_type(8)));
typedef float  f32x4  __attribute__((ext_vector_type(4)));
typedef unsigned short ushort4v __attribute__((ext_vector_type(4)));

// ---- contraction-proof f32 ops (round exactly like numpy's elementwise)
__device__ __forceinline__ float mul_rn(float a, float b) {
#pragma clang fp contract(off)
    return a * b;
}
__device__ __forceinline__ float add_rn(float a, float b) {
#pragma clang fp contract(off)
    return a + b;
}
__device__ __forceinline__ float sub_rn(float a, float b) {
#pragma clang fp contract(off)
    return a - b;
}

__device__ __forceinline__ unsigned short f32_bf16_rn(float f) {
    unsigned u = __float_as_uint(f);
    return (unsigned short)((u + 0x7FFFu + ((u >> 16) & 1u)) >> 16);
}
__device__ __forceinline__ float bf16_f32(unsigned short h) {
    return __uint_as_float((unsigned)h << 16);
}

__device__ __forceinline__ void async16(const void* g, void* l) {
    __builtin_amdgcn_global_load_lds(
        (const __attribute__((address_space(1))) unsigned int*)g,
        (__attribute__((address_space(3))) unsigned int*)l, 16, 0, 0);
}

// numpy pairwise_sum replica for 256 f32 squares (8 chains stride 8, tree merge)
template <typename LOAD>
__device__ __forceinline__ float np_sumsq_256(LOAD ld) {
    float blk[2];
    #pragma unroll
    for (int h = 0; h < 2; ++h) {
        const int base = h * 128;
        float r[8];
        #pragma unroll
        for (int j = 0; j < 8; ++j) {
            float v = ld(base + j);
            r[j] = mul_rn(v, v);
        }
        for (int i = 8; i < 128; i += 8) {
            #pragma unroll
            for (int j = 0; j < 8; ++j) {
                float v = ld(base + i + j);
                r[j] = add_rn(r[j], mul_rn(v, v));
            }
        }
        blk[h] = add_rn(add_rn(add_rn(r[0], r[1]), add_rn(r[2], r[3])),
                        add_rn(add_rn(r[4], r[5]), add_rn(r[6], r[7])));
    }
    return add_rn(blk[0], blk[1]);
}

// ---------------- K1: split x -> Xs[n][768] bf16  ([hi | lo | hi-dup])
// x is [16][256][32][32]; n = b*1024+hw, k = d  (transpose via LDS)
__global__ __launch_bounds__(256)
void split_x_kernel(const float* __restrict__ x, unsigned short* __restrict__ Xs) {
    __shared__ float t[32][33];
    const int tid = threadIdx.x;
    const int tx = tid & 31, ty = tid >> 5;
    const int ht = blockIdx.x & 31;          // hw tile
    const int dt = (blockIdx.x >> 5) & 7;    // d tile
    const int b  = blockIdx.x >> 8;          // batch
    #pragma unroll
    for (int r = 0; r < 4; ++r) {
        int dl = ty + 8 * r;
        t[dl][tx] = x[(size_t)(b * 256 + dt * 32 + dl) * BHW + ht * 32 + tx];
    }
    __syncthreads();
    #pragma unroll
    for (int r = 0; r < 4; ++r) {
        int hwl = ty + 8 * r;
        int n = b * BHW + ht * 32 + hwl;
        float f = t[tx][hwl];
        unsigned short hi = f32_bf16_rn(f);
        unsigned short lo = f32_bf16_rn(f - bf16_f32(hi));
        size_t base = (size_t)n * KS + dt * 32 + tx;
        Xs[base]       = hi;
        Xs[base + 256] = lo;
        Xs[base + 512] = hi;
    }
}

// ---------------- K2: split cb -> Cs[k][768] bf16 ([hi | hi-dup | lo])
__global__ __launch_bounds__(256)
void split_c_kernel(const float* __restrict__ cb, unsigned short* __restrict__ Cs) {
    int t = blockIdx.x * 256 + threadIdx.x;     // one float4 of cb (524288 total)
    int k = t >> 6, d = (t & 63) * 4;
    float4 v = ((const float4*)cb)[t];
    ushort4v hi, lo;
    hi.x = f32_bf16_rn(v.x); lo.x = f32_bf16_rn(v.x - bf16_f32(hi.x));
    hi.y = f32_bf16_rn(v.y); lo.y = f32_bf16_rn(v.y - bf16_f32(hi.y));
    hi.z = f32_bf16_rn(v.z); lo.z = f32_bf16_rn(v.z - bf16_f32(hi.z));
    hi.w = f32_bf16_rn(v.w); lo.w = f32_bf16_rn(v.w - bf16_f32(hi.w));
    size_t base = (size_t)k * KS + d;
    *(ushort4v*)(Cs + base)       = hi;
    *(ushort4v*)(Cs + base + 256) = hi;
    *(ushort4v*)(Cs + base + 512) = lo;
}

// ---------------- K3: c_sq (np-exact)
__global__ __launch_bounds__(256)
void csq_kernel(const float* __restrict__ cb, float* __restrict__ csq) {
    int k = blockIdx.x * 256 + threadIdx.x;
    if (k >= K) return;
    const float* row = cb + (size_t)k * D;
    csq[k] = np_sumsq_256([&](int d) { return row[d]; });
}

// ---------------- K4: x_sq (np-exact)
__global__ __launch_bounds__(256)
void xsq_kernel(const float* __restrict__ x, float* __restrict__ xsq) {
    int n = blockIdx.x * 256 + threadIdx.x;
    if (n >= NROWS) return;
    int b = n >> 10, hw = n & 1023;
    const float* p = x + (size_t)b * (D * BHW) + hw;
    xsq[n] = np_sumsq_256([&](int d) { return p[(size_t)d * BHW]; });
}

// ---------------- K5: MFMA screen gemm: localmin[n][64] = min over 128-code
// block of (csq[k] - 2*dot~(x[n],c[k]))
__global__ __launch_bounds__(256)
void screen_kernel(const unsigned short* __restrict__ Xs,  // [16384][768]
                   const unsigned short* __restrict__ Cs,  // [8192][768]
                   const float* __restrict__ csq,
                   float* __restrict__ localmin) {          // [16384][64]
    __shared__ __align__(16) unsigned short As[128 * 32];   // [row][32k] 8 KB
    __shared__ __align__(16) unsigned short Bs[128 * 32];   // [code][32k] 8 KB
    __shared__ float lm[128 * 2];

    const int tid = threadIdx.x;
    const int w   = tid >> 6;       // wave 0..3
    const int ln  = tid & 63;
    const int bx = blockIdx.x, by = blockIdx.y;

    // staging: wave w stages rows [32w, 32w+32) of both tiles; 16B/lane/instr
    const int arow = bx * 128 + 32 * w + (ln >> 2);
    const int brow = by * 128 + 32 * w + (ln >> 2);
    const unsigned short* ga0 = Xs + (size_t)arow * KS + (ln & 3) * 8;
    const unsigned short* ga1 = ga0 + (size_t)16 * KS;
    const unsigned short* gb0 = Cs + (size_t)brow * KS + (ln & 3) * 8;
    const unsigned short* gb1 = gb0 + (size_t)16 * KS;
    char* lA = (char*)As + (2 * w) * 1024;   // wave-uniform LDS dest
    char* lB = (char*)Bs + (2 * w) * 1024;

    // compute mapping: wave -> 64x64 quadrant
    const int rh = (w & 1) * 64;    // row half
    const int ch = (w >> 1) * 64;   // col half

    f32x4 acc[4][4] = {};

    for (int ks = 0; ks < KS / 32; ++ks) {     // 24 k-steps
        const int kb = ks * 32;
        async16(ga0 + kb, lA);
        async16(ga1 + kb, lA + 1024);
        async16(gb0 + kb, lB);
        async16(gb1 + kb, lB + 1024);
        __syncthreads();      // drains vmcnt -> LDS valid
        bf16x8 af[4], bf[4];
        #pragma unroll
        for (int t = 0; t < 4; ++t) {
            af[t] = *(const bf16x8*)((const char*)As + (rh + t * 16 + (ln & 15)) * 64 + (ln >> 4) * 16);
            bf[t] = *(const bf16x8*)((const char*)Bs + (ch + t * 16 + (ln & 15)) * 64 + (ln >> 4) * 16);
        }
        #pragma unroll
        for (int i = 0; i < 4; ++i)
            #pragma unroll
            for (int j = 0; j < 4; ++j)
                acc[i][j] = __builtin_amdgcn_mfma_f32_16x16x32_bf16(af[i], bf[j], acc[i][j], 0, 0, 0);
        __syncthreads();      // before next-iter LDS overwrite
    }

    // epilogue: s = csq - 2*acc; per-row min over this block's 128 cols
    float cq[4];
    #pragma unroll
    for (int j = 0; j < 4; ++j)
        cq[j] = csq[by * 128 + ch + j * 16 + (ln & 15)];
    float pm[4][4];
    #pragma unroll
    for (int i = 0; i < 4; ++i)
        #pragma unroll
        for (int r = 0; r < 4; ++r) {
            float m = cq[0] - 2.0f * acc[i][0][r];
            #pragma unroll
            for (int j = 1; j < 4; ++j)
                m = fminf(m, cq[j] - 2.0f * acc[i][j][r]);
            pm[i][r] = m;
        }
    #pragma unroll
    for (int msk = 1; msk < 16; msk <<= 1)
        #pragma unroll
        for (int i = 0; i < 4; ++i)
            #pragma unroll
            for (int r = 0; r < 4; ++r)
                pm[i][r] = fminf(pm[i][r], __shfl_xor(pm[i][r], msk, 64));
    if ((ln & 15) == 0) {
        #pragma unroll
        for (int i = 0; i < 4; ++i)
            #pragma unroll
            for (int r = 0; r < 4; ++r)
                lm[(rh + i * 16 + (ln >> 4) * 4 + r) * 2 + (w >> 1)] = pm[i][r];
    }
    __syncthreads();
    if (tid < 128)
        localmin[(size_t)(bx * 128 + tid) * 64 + by] = fminf(lm[tid * 2], lm[tid * 2 + 1]);
}

// ---------------- K6: per-row gmin + candidate-block mask (64 blocks = 64 lanes)
__global__ __launch_bounds__(256)
void flag_kernel(const float* __restrict__ localmin, unsigned long long* __restrict__ candmask) {
    const int tid = threadIdx.x;
    const int w = tid >> 6, ln = tid & 63;
    const int n = blockIdx.x * 4 + w;
    float lm = localmin[(size_t)n * 64 + ln];
    float g = lm;
    #pragma unroll
    for (int m = 1; m < 64; m <<= 1) g = fminf(g, __shfl_xor(g, m, 64));
    unsigned long long mask = __ballot(lm <= g + MARGIN);
    if (ln == 0) candmask[n] = mask;
}

// ---------------- K7: exact rescore of flagged blocks -> idx[n]
__global__ __launch_bounds__(256)
void rescore_kernel(const float* __restrict__ x, const float* __restrict__ cb,
                    const float* __restrict__ csq, const float* __restrict__ xsq,
                    const unsigned long long* __restrict__ candmask,
                    int* __restrict__ idx) {
    __shared__ float xrow[256];
    __shared__ float sred[4];
    __shared__ int   ired[4];
    const int tid = threadIdx.x;
    const int n = blockIdx.x;
    const int b = n >> 10, hw = n & 1023;
    xrow[tid] = x[(size_t)(b * 256 + tid) * BHW + hw];
    __syncthreads();
    unsigned long long mask = candmask[n];
    const float xs = xsq[n];
    float bs = FLT_MAX;
    int   bk = 0x7fffffff;
    const int code_off = tid >> 1, half = tid & 1;
    while (mask) {
        int cbk = (int)__builtin_ctzll(mask);
        mask &= mask - 1;
        int k = cbk * 128 + code_off;
        const float4* cp = (const float4*)(cb + (size_t)k * D + half * 128);
        const float*  xr = xrow + half * 128;
        double acc = 0.0;
        #pragma unroll 8
        for (int i = 0; i < 32; ++i) {
            float4 v = cp[i];
            acc += (double)v.x * xr[i * 4 + 0] + (double)v.y * xr[i * 4 + 1]
                 + (double)v.z * xr[i * 4 + 2] + (double)v.w * xr[i * 4 + 3];
        }
        double other = __shfl_xor(acc, 1, 64);
        float dot = (float)(acc + other);
        float s = sub_rn(add_rn(xs, csq[k]), mul_rn(2.0f, dot));
        if (s < bs || (s == bs && k < bk)) { bs = s; bk = k; }
    }
    // wave reduce (lexicographic: score, then smaller index)
    #pragma unroll
    for (int m = 1; m < 64; m <<= 1) {
        float os = __shfl_xor(bs, m, 64);
        int   ok = __shfl_xor(bk, m, 64);
        if (os < bs || (os == bs && ok < bk)) { bs = os; bk = ok; }
    }
    if ((tid & 63) == 0) { sred[tid >> 6] = bs; ired[tid >> 6] = bk; }
    __syncthreads();
    if (tid == 0) {
        float fbs = sred[0]; int fbk = ired[0];
        #pragma unroll
        for (int wv = 1; wv < 4; ++wv) {
            if (sred[wv] < fbs || (sred[wv] == fbs && ired[wv] < fbk)) { fbs = sred[wv]; fbk = ired[wv]; }
        }
        idx[n] = fbk;
    }
}

// ---------------- K8: quantized gather back to (B,C,H,W)
__global__ __launch_bounds__(256)
void gather_quant_kernel(const float* __restrict__ cb, const int* __restrict__ idx,
                         float* __restrict__ out0) {
    int t = blockIdx.x * 256 + threadIdx.x;
    int hw4 = t & 255;
    int d   = (t >> 8) & 255;
    int b   = t >> 16;
    int n0  = b * BHW + hw4 * 4;
    float4 o;
    o.x = cb[(size_t)idx[n0 + 0] * D + d];
    o.y = cb[(size_t)idx[n0 + 1] * D + d];
    o.z = cb[(size_t)idx[n0 + 2] * D + d];
    o.w = cb[(size_t)idx[n0 + 3] * D + d];
    ((float4*)out0)[t] = o;
}

// ---------------- K9: one-hot fill
__global__ __launch_bounds__(256)
void onehot_kernel(const int* __restrict__ idx, float* __restrict__ out1) {
    int t = blockIdx.x * 256 + threadIdx.x;
    int n  = t >> 11;
    int k0 = (t & 2047) * 4;
    int target = idx[n];
    float4 v = {0.f, 0.f, 0.f, 0.f};
    int r = target - k0;
    if (r >= 0 && r < 4) ((float*)&v)[r] = 1.0f;
    ((float4*)out1)[t] = v;
}

// ------------------------------------------------------------------ launch
extern "C" void kernel_launch(void* const* d_in, const int* in_sizes, int n_in,
                              void* d_out, int out_size, void* d_ws, size_t ws_size,
                              hipStream_t stream) {
    const float* x  = (const float*)d_in[0];   // [16][256][32][32]
    const float* cb = (const float*)d_in[1];   // [8192][256]
    float* out0 = (float*)d_out;                       // quantized: 4,194,304 floats
    float* out1 = (float*)d_out + 4194304;             // one_hot:  134,217,728 floats

    // small scratch in ws
    char* ws = (char*)d_ws;
    float* csq  = (float*)(ws + 0);            //  8192 f32 (32 KB)
    float* xsq  = (float*)(ws + 32768);        // 16384 f32 (64 KB)
    int*   idx  = (int*)  (ws + 98304);        // 16384 i32 (64 KB)
    unsigned long long* candmask = (unsigned long long*)(ws + 163840);  // 128 KB

    // big scratch in the one_hot output region (overwritten last by onehot)
    char* sc = (char*)out1;
    unsigned short* Xs = (unsigned short*)sc;                       // 25,165,824 B
    unsigned short* Cs = (unsigned short*)(sc + 25165824);          // 12,582,912 B
    float* localmin    = (float*)(sc + 37748736);                   //  4,194,304 B

    split_x_kernel<<<4096, 256, 0, stream>>>(x, Xs);
    split_c_kernel<<<2048, 256, 0, stream>>>(cb, Cs);
    csq_kernel<<<K / 256, 256, 0, stream>>>(cb, csq);
    xsq_kernel<<<NROWS / 256, 256, 0, stream>>>(x, xsq);

    dim3 sgrid(NROWS / 128, K / 128);   // 128 x 64
    screen_kernel<<<sgrid, 256, 0, stream>>>(Xs, Cs, csq, localmin);

    flag_kernel<<<NROWS / 4, 256, 0, stream>>>(localmin, candmask);
    rescore_kernel<<<NROWS, 256, 0, stream>>>(x, cb, csq, xsq, candmask, idx);

    gather_quant_kernel<<<(4194304 / 4) / 256, 256, 0, stream>>>(cb, idx, out0);
    onehot_kernel<<<(134217728 / 4) / 256, 256, 0, stream>>>(idx, out1);
}

// Round 6
// 996.012 us; speedup vs baseline: 1.4109x; 1.2561x over previous
//
#include <hip/hip_runtime.h>
#include <float.h>
#include <stdint.h>

// Problem constants
constexpr int D      = 256;
constexpr int K      = 8192;
constexpr int NROWS  = 16384;   // 16 * 32 * 32
constexpr int BHW    = 1024;
constexpr int CAP    = 128;     // max candidates per row (64 blocks * 2)
constexpr float MARGIN = 8e-4f; // >= 2E = 5.8e-4 rigorous bound (see notes)

typedef __bf16 bf16x8 __attribute__((ext_vector_type(8)));
typedef float  f32x4  __attribute__((ext_vector_type(4)));
typedef unsigned short ushort4v __attribute__((ext_vector_type(4)));

// ---- contraction-proof f32 ops (round exactly like numpy's elementwise)
__device__ __forceinline__ float mul_rn(float a, float b) {
#pragma clang fp contract(off)
    return a * b;
}
__device__ __forceinline__ float add_rn(float a, float b) {
#pragma clang fp contract(off)
    return a + b;
}
__device__ __forceinline__ float sub_rn(float a, float b) {
#pragma clang fp contract(off)
    return a - b;
}

__device__ __forceinline__ unsigned short f32_bf16_rn(float f) {
    unsigned u = __float_as_uint(f);
    return (unsigned short)((u + 0x7FFFu + ((u >> 16) & 1u)) >> 16);
}

__device__ __forceinline__ void async16(const void* g, void* l) {
    __builtin_amdgcn_global_load_lds(
        (const __attribute__((address_space(1))) unsigned int*)g,
        (__attribute__((address_space(3))) unsigned int*)l, 16, 0, 0);
}

// sorted-3 insert: keep 3 smallest, indices for slots 0,1 only
__device__ __forceinline__ void ins3(float s, int kg, float& v0, int& i0,
                                     float& v1, int& i1, float& v2) {
    if (s < v0)      { v2 = v1; v1 = v0; i1 = i0; v0 = s; i0 = kg; }
    else if (s < v1) { v2 = v1; v1 = s; i1 = kg; }
    else if (s < v2) { v2 = s; }
}

// numpy pairwise_sum replica for 256 f32 squares (8 chains stride 8, tree merge)
template <typename LOAD>
__device__ __forceinline__ float np_sumsq_256(LOAD ld) {
    float blk[2];
    #pragma unroll
    for (int h = 0; h < 2; ++h) {
        const int base = h * 128;
        float r[8];
        #pragma unroll
        for (int j = 0; j < 8; ++j) {
            float v = ld(base + j);
            r[j] = mul_rn(v, v);
        }
        for (int i = 8; i < 128; i += 8) {
            #pragma unroll
            for (int j = 0; j < 8; ++j) {
                float v = ld(base + i + j);
                r[j] = add_rn(r[j], mul_rn(v, v));
            }
        }
        blk[h] = add_rn(add_rn(add_rn(r[0], r[1]), add_rn(r[2], r[3])),
                        add_rn(add_rn(r[4], r[5]), add_rn(r[6], r[7])));
    }
    return add_rn(blk[0], blk[1]);
}

// ---------------- K1: x (B,C,H,W) -> xT[n][256] f32 + Xbf[n][256] bf16
__global__ __launch_bounds__(256)
void prep_x_kernel(const float* __restrict__ x, float* __restrict__ xT,
                   unsigned short* __restrict__ Xbf) {
    __shared__ float t[32][33];
    const int tid = threadIdx.x;
    const int tx = tid & 31, ty = tid >> 5;
    const int ht = blockIdx.x & 31;
    const int dt = (blockIdx.x >> 5) & 7;
    const int b  = blockIdx.x >> 8;
    #pragma unroll
    for (int r = 0; r < 4; ++r) {
        int dl = ty + 8 * r;
        t[dl][tx] = x[(size_t)(b * 256 + dt * 32 + dl) * BHW + ht * 32 + tx];
    }
    __syncthreads();
    #pragma unroll
    for (int r = 0; r < 4; ++r) {
        int hwl = ty + 8 * r;
        int n = b * BHW + ht * 32 + hwl;
        float f = t[tx][hwl];
        xT[(size_t)n * 256 + dt * 32 + tx] = f;
        Xbf[(size_t)n * 256 + dt * 32 + tx] = f32_bf16_rn(f);
    }
}

// ---------------- K2: cb -> Cbf bf16
__global__ __launch_bounds__(256)
void prep_c_kernel(const float* __restrict__ cb, unsigned short* __restrict__ Cbf) {
    int t = blockIdx.x * 256 + threadIdx.x;   // one float4 (524288 total)
    float4 v = ((const float4*)cb)[t];
    ushort4v h;
    h.x = f32_bf16_rn(v.x); h.y = f32_bf16_rn(v.y);
    h.z = f32_bf16_rn(v.z); h.w = f32_bf16_rn(v.w);
    *(ushort4v*)(Cbf + (size_t)t * 4) = h;
}

// ---------------- K3: c_sq (np-exact)
__global__ __launch_bounds__(256)
void csq_kernel(const float* __restrict__ cb, float* __restrict__ csq) {
    int k = blockIdx.x * 256 + threadIdx.x;
    if (k >= K) return;
    const float* row = cb + (size_t)k * D;
    csq[k] = np_sumsq_256([&](int d) { return row[d]; });
}

// ---------------- K4: x_sq (np-exact, from xT)
__global__ __launch_bounds__(256)
void xsq_kernel(const float* __restrict__ xT, float* __restrict__ xsq) {
    int n = blockIdx.x * 256 + threadIdx.x;
    if (n >= NROWS) return;
    const float* row = xT + (size_t)n * 256;
    xsq[n] = np_sumsq_256([&](int d) { return row[d]; });
}

// ---------------- K5: bf16 MFMA screen, top-3 per (row, 128-code block)
// s~[n][k] = csq[k] - 2*dot_bf16(x[n],c[k]);  outputs laid out [block][n]
__global__ __launch_bounds__(256)
void screen_kernel(const unsigned short* __restrict__ Xbf,  // [16384][256]
                   const unsigned short* __restrict__ Cbf,  // [8192][256]
                   const float* __restrict__ csq,
                   float* __restrict__ sv0, float* __restrict__ sv1,
                   float* __restrict__ sv2,
                   int* __restrict__ si0, int* __restrict__ si1) {
    __shared__ __align__(16) unsigned short As[128 * 32];   // [row][32k] 8 KB
    __shared__ __align__(16) unsigned short Bs[128 * 32];

    const int tid = threadIdx.x;
    const int w   = tid >> 6;
    const int ln  = tid & 63;
    const int bx = blockIdx.x, by = blockIdx.y;

    const int arow = bx * 128 + 32 * w + (ln >> 2);
    const int brow = by * 128 + 32 * w + (ln >> 2);
    const unsigned short* ga0 = Xbf + (size_t)arow * 256 + (ln & 3) * 8;
    const unsigned short* ga1 = ga0 + (size_t)16 * 256;
    const unsigned short* gb0 = Cbf + (size_t)brow * 256 + (ln & 3) * 8;
    const unsigned short* gb1 = gb0 + (size_t)16 * 256;
    char* lA = (char*)As + (2 * w) * 1024;
    char* lB = (char*)Bs + (2 * w) * 1024;

    const int rh = (w & 1) * 64;
    const int ch = (w >> 1) * 64;

    f32x4 acc[4][4] = {};

    for (int ks = 0; ks < 8; ++ks) {          // K = 256, BK = 32
        const int kb = ks * 32;
        async16(ga0 + kb, lA);
        async16(ga1 + kb, lA + 1024);
        async16(gb0 + kb, lB);
        async16(gb1 + kb, lB + 1024);
        __syncthreads();
        bf16x8 af[4], bfr[4];
        #pragma unroll
        for (int t = 0; t < 4; ++t) {
            af[t]  = *(const bf16x8*)((const char*)As + (rh + t * 16 + (ln & 15)) * 64 + (ln >> 4) * 16);
            bfr[t] = *(const bf16x8*)((const char*)Bs + (ch + t * 16 + (ln & 15)) * 64 + (ln >> 4) * 16);
        }
        #pragma unroll
        for (int i = 0; i < 4; ++i)
            #pragma unroll
            for (int j = 0; j < 4; ++j)
                acc[i][j] = __builtin_amdgcn_mfma_f32_16x16x32_bf16(af[i], bfr[j], acc[i][j], 0, 0, 0);
        __syncthreads();
    }

    // epilogue: per (row, this wave's 64 cols) top-3 with indices for top-2
    float cq[4];
    #pragma unroll
    for (int j = 0; j < 4; ++j)
        cq[j] = csq[by * 128 + ch + j * 16 + (ln & 15)];

    // LDS overlay (tiles dead after last barrier)
    float* lmv0 = (float*)As;            // [128][2]
    float* lmv1 = lmv0 + 256;
    float* lmv2 = lmv1 + 256;
    int*   lmi0 = (int*)(lmv2 + 256);
    int*   lmi1 = lmi0 + 256;

    #pragma unroll
    for (int i = 0; i < 4; ++i)
        #pragma unroll
        for (int r = 0; r < 4; ++r) {
            float v0 = FLT_MAX, v1 = FLT_MAX, v2 = FLT_MAX;
            int i0 = 0, i1 = 0;
            #pragma unroll
            for (int j = 0; j < 4; ++j) {
                float s = cq[j] - 2.0f * acc[i][j][r];
                int kg = by * 128 + ch + j * 16 + (ln & 15);
                ins3(s, kg, v0, i0, v1, i1, v2);
            }
            #pragma unroll
            for (int m = 1; m < 16; m <<= 1) {
                float w0 = __shfl_xor(v0, m, 64); int u0 = __shfl_xor(i0, m, 64);
                float w1 = __shfl_xor(v1, m, 64); int u1 = __shfl_xor(i1, m, 64);
                float w2 = __shfl_xor(v2, m, 64);
                ins3(w0, u0, v0, i0, v1, i1, v2);
                ins3(w1, u1, v0, i0, v1, i1, v2);
                v2 = fminf(v2, w2);
            }
            if ((ln & 15) == 0) {
                int lrow = rh + i * 16 + (ln >> 4) * 4 + r;
                int half = w >> 1;
                lmv0[lrow * 2 + half] = v0;
                lmv1[lrow * 2 + half] = v1;
                lmv2[lrow * 2 + half] = v2;
                lmi0[lrow * 2 + half] = i0;
                lmi1[lrow * 2 + half] = i1;
            }
        }
    __syncthreads();
    if (tid < 128) {
        float v0 = lmv0[tid * 2], v1 = lmv1[tid * 2], v2 = lmv2[tid * 2];
        int i0 = lmi0[tid * 2], i1 = lmi1[tid * 2];
        ins3(lmv0[tid * 2 + 1], lmi0[tid * 2 + 1], v0, i0, v1, i1, v2);
        ins3(lmv1[tid * 2 + 1], lmi1[tid * 2 + 1], v0, i0, v1, i1, v2);
        v2 = fminf(v2, lmv2[tid * 2 + 1]);
        size_t o = (size_t)by * NROWS + bx * 128 + tid;
        sv0[o] = v0; sv1[o] = v1; sv2[o] = v2; si0[o] = i0; si1[o] = i1;
    }
}

// ---------------- K6: per-row thresh + candidate list (+ rare full-scan mask)
__global__ __launch_bounds__(256)
void flag_kernel(const float* __restrict__ sv0, const float* __restrict__ sv1,
                 const float* __restrict__ sv2,
                 const int* __restrict__ si0, const int* __restrict__ si1,
                 int* __restrict__ cand, int* __restrict__ count,
                 unsigned long long* __restrict__ fsmask) {
    __shared__ float tile[64][65];
    __shared__ float thrS[64];
    __shared__ unsigned long long m1s[64], m2s[64], m3s[64];
    const int tid = threadIdx.x;
    const int ln = tid & 63, w = tid >> 6;
    const int n0 = blockIdx.x * 64;

    for (int b = w; b < 64; b += 4) tile[ln][b] = sv0[(size_t)b * NROWS + n0 + ln];
    __syncthreads();
    for (int rr = 0; rr < 16; ++rr) {
        int row = w * 16 + rr;
        float v = tile[row][ln];
        float g = v;
        #pragma unroll
        for (int m = 1; m < 64; m <<= 1) g = fminf(g, __shfl_xor(g, m, 64));
        float th = g + MARGIN;
        unsigned long long m1 = __ballot(v <= th);
        if (ln == 0) { thrS[row] = th; m1s[row] = m1; }
    }
    __syncthreads();
    for (int b = w; b < 64; b += 4) tile[ln][b] = sv1[(size_t)b * NROWS + n0 + ln];
    __syncthreads();
    for (int rr = 0; rr < 16; ++rr) {
        int row = w * 16 + rr;
        unsigned long long m2 = __ballot(tile[row][ln] <= thrS[row]);
        if (ln == 0) m2s[row] = m2;
    }
    __syncthreads();
    for (int b = w; b < 64; b += 4) tile[ln][b] = sv2[(size_t)b * NROWS + n0 + ln];
    __syncthreads();
    for (int rr = 0; rr < 16; ++rr) {
        int row = w * 16 + rr;
        unsigned long long m3 = __ballot(tile[row][ln] <= thrS[row]);
        if (ln == 0) m3s[row] = m3;
    }
    __syncthreads();
    for (int rr = 0; rr < 16; ++rr) {
        int row = w * 16 + rr;
        int n = n0 + row;
        unsigned long long m1 = m1s[row], m2 = m2s[row];
        int c1 = __popcll(m1);
        if ((m1 >> ln) & 1) {
            int pos = __popcll(m1 & ((1ull << ln) - 1ull));
            cand[(size_t)n * CAP + pos] = si0[(size_t)ln * NROWS + n];
        }
        if ((m2 >> ln) & 1) {
            int pos = c1 + __popcll(m2 & ((1ull << ln) - 1ull));
            cand[(size_t)n * CAP + pos] = si1[(size_t)ln * NROWS + n];
        }
        if (ln == 0) {
            count[n] = c1 + __popcll(m2);
            fsmask[n] = m3s[row];
        }
    }
}

// ---------------- K7: exact rescore of candidate codes -> idx[n]
__global__ __launch_bounds__(256)
void rescore_kernel(const float* __restrict__ xT, const float* __restrict__ cb,
                    const float* __restrict__ csq, const float* __restrict__ xsq,
                    const int* __restrict__ cand, const int* __restrict__ count,
                    const unsigned long long* __restrict__ fsmask,
                    int* __restrict__ idx) {
    const int tid = threadIdx.x;
    const int w = tid >> 6, ln = tid & 63;
    const int n = blockIdx.x * 4 + w;
    float4 xv = ((const float4*)xT)[(size_t)n * 64 + ln];
    const float xs = xsq[n];
    const int cnt = count[n];
    unsigned long long fs = fsmask[n];
    float bs = FLT_MAX;
    int   bk = 0x7fffffff;
    auto eval = [&](int k) {
        float4 cv = ((const float4*)cb)[(size_t)k * 64 + ln];
        double d = (double)cv.x * xv.x + (double)cv.y * xv.y
                 + (double)cv.z * xv.z + (double)cv.w * xv.w;
        #pragma unroll
        for (int m = 1; m < 64; m <<= 1) d += __shfl_xor(d, m, 64);
        float s = sub_rn(add_rn(xs, csq[k]), mul_rn(2.0f, (float)d));
        if (s < bs || (s == bs && k < bk)) { bs = s; bk = k; }
    };
    for (int c = 0; c < cnt; ++c) eval(cand[(size_t)n * CAP + c]);
    while (fs) {           // rare rigorous fallback: >2 near-ties in one block
        int b = (int)__builtin_ctzll(fs);
        fs &= fs - 1;
        for (int kk = 0; kk < 128; ++kk) eval(b * 128 + kk);
    }
    if (ln == 0) idx[n] = bk;
}

// ---------------- K8: quantized gather back to (B,C,H,W)
__global__ __launch_bounds__(256)
void gather_quant_kernel(const float* __restrict__ cb, const int* __restrict__ idx,
                         float* __restrict__ out0) {
    int t = blockIdx.x * 256 + threadIdx.x;
    int hw4 = t & 255;
    int d   = (t >> 8) & 255;
    int b   = t >> 16;
    int n0  = b * BHW + hw4 * 4;
    float4 o;
    o.x = cb[(size_t)idx[n0 + 0] * D + d];
    o.y = cb[(size_t)idx[n0 + 1] * D + d];
    o.z = cb[(size_t)idx[n0 + 2] * D + d];
    o.w = cb[(size_t)idx[n0 + 3] * D + d];
    ((float4*)out0)[t] = o;
}

// ---------------- K9: one-hot fill
__global__ __launch_bounds__(256)
void onehot_kernel(const int* __restrict__ idx, float* __restrict__ out1) {
    int t = blockIdx.x * 256 + threadIdx.x;
    int n  = t >> 11;
    int k0 = (t & 2047) * 4;
    int target = idx[n];
    float4 v = {0.f, 0.f, 0.f, 0.f};
    int r = target - k0;
    if (r >= 0 && r < 4) ((float*)&v)[r] = 1.0f;
    ((float4*)out1)[t] = v;
}

// ------------------------------------------------------------------ launch
extern "C" void kernel_launch(void* const* d_in, const int* in_sizes, int n_in,
                              void* d_out, int out_size, void* d_ws, size_t ws_size,
                              hipStream_t stream) {
    const float* x  = (const float*)d_in[0];   // [16][256][32][32]
    const float* cb = (const float*)d_in[1];   // [8192][256]
    float* out0 = (float*)d_out;                       // quantized
    float* out1 = (float*)d_out + 4194304;             // one_hot (537 MB)

    // small scratch in ws
    char* ws = (char*)d_ws;
    float* csq  = (float*)(ws + 0);            //  32 KB
    float* xsq  = (float*)(ws + 32768);        //  64 KB
    int*   idx  = (int*)  (ws + 98304);        //  64 KB
    int*   cnt  = (int*)  (ws + 163840);       //  64 KB
    unsigned long long* fsm = (unsigned long long*)(ws + 229376);  // 128 KB

    // big scratch in the one_hot region (fully overwritten last by onehot)
    char* sc = (char*)out1;
    unsigned short* Xbf = (unsigned short*)sc;                   //  8 MB
    unsigned short* Cbf = (unsigned short*)(sc + 8388608);       //  4 MB
    float* xT  = (float*)(sc + 12582912);                        // 16 MB
    float* sv0 = (float*)(sc + 29360128);                        //  4 MB
    float* sv1 = (float*)(sc + 33554432);
    float* sv2 = (float*)(sc + 37748736);
    int*   si0 = (int*)  (sc + 41943040);
    int*   si1 = (int*)  (sc + 46137344);
    int*   cand = (int*) (sc + 50331648);                        //  8 MB

    prep_x_kernel<<<4096, 256, 0, stream>>>(x, xT, Xbf);
    prep_c_kernel<<<2048, 256, 0, stream>>>(cb, Cbf);
    csq_kernel<<<K / 256, 256, 0, stream>>>(cb, csq);
    xsq_kernel<<<NROWS / 256, 256, 0, stream>>>(xT, xsq);

    dim3 sgrid(NROWS / 128, K / 128);   // 128 x 64
    screen_kernel<<<sgrid, 256, 0, stream>>>(Xbf, Cbf, csq, sv0, sv1, sv2, si0, si1);

    flag_kernel<<<NROWS / 64, 256, 0, stream>>>(sv0, sv1, sv2, si0, si1, cand, cnt, fsm);
    rescore_kernel<<<NROWS / 4, 256, 0, stream>>>(xT, cb, csq, xsq, cand, cnt, fsm, idx);

    gather_quant_kernel<<<(4194304 / 4) / 256, 256, 0, stream>>>(cb, idx, out0);
    onehot_kernel<<<(134217728 / 4) / 256, 256, 0, stream>>>(idx, out1);
}